// Round 4
// baseline (451.302 us; speedup 1.0000x reference)
//
#include <hip/hip_runtime.h>

#define NVOX 32000
#define NPTS 1024000
#define NBLK 1000      // k2/k3 blocks (4 waves each -> 4000 waves)
#define NWAV 4000
#define VPW  8         // voxels per wave: 4000*8 = 32000

typedef __attribute__((ext_vector_type(8)))  short bf8v;   // 8 bf16 (4 VGPRs)
typedef __attribute__((ext_vector_type(16))) float f16x;   // MFMA 32x32 accum

// split x = hi + lo (both trunc-bf16); residual error ~2^-16 relative
__device__ __forceinline__ void split2(float x, short* hi, short* lo) {
    const unsigned u = __float_as_uint(x);
    *hi = (short)(u >> 16);
    const float r = x - __uint_as_float(u & 0xFFFF0000u);   // exact
    *lo = (short)(__float_as_uint(r) >> 16);
}
__device__ __forceinline__ float rdlane(float v, int l) {
    return __int_as_float(__builtin_amdgcn_readlane(__float_as_int(v), l));
}

// ws float offsets
#define O_W1S  0        // 128
#define O_C1S  128      // 16
#define O_A2C2 160      // 64  (a2[32], c2[32])
#define O_AFCF 224      // 128 (af[64], cf[64])
#define O_P1   352      // 1024*32
#define O_P2   (O_P1 + 1024*32)      // 1000*64
#define O_P3   (O_P2 + 1000*64)      // 1000*128

// ---------------- k1: partial stats of h1pre (16 ch) over all points ----------------
__global__ __launch_bounds__(256) void k1(const float* __restrict__ vox,
                                          const int* __restrict__ coords,
                                          const float* __restrict__ W1,
                                          float* __restrict__ p1) {
    float sum[16], sq[16];
#pragma unroll
    for (int o = 0; o < 16; o++) { sum[o] = 0.f; sq[o] = 0.f; }
    const int stride = gridDim.x * blockDim.x;
    for (int i = blockIdx.x * blockDim.x + threadIdx.x; i < NPTS; i += stride) {
        const int vx = i >> 5;
        const float4 q = reinterpret_cast<const float4*>(vox)[i];
        const int4 c4 = reinterpret_cast<const int4*>(coords)[vx];
        const float cx = ((float)c4.w + 0.5f) * 0.16f;
        const float cy = ((float)c4.z + 0.5f) * 0.16f - 39.68f;
        const float cz = ((float)c4.y + 0.5f) * 4.0f  - 3.0f;
        const float f[8] = {q.x, q.y, q.z, q.x - cx, q.y - cy, q.z - cz, q.w, q.z};
#pragma unroll
        for (int o = 0; o < 16; o++) {
            float h = 0.f;
#pragma unroll
            for (int c = 0; c < 8; c++) h = fmaf(f[c], W1[o * 8 + c], h);
            sum[o] += h;
            sq[o] = fmaf(h, h, sq[o]);
        }
    }
    __shared__ float red[4][32];
    const int lane = threadIdx.x & 63, wv = threadIdx.x >> 6;
#pragma unroll
    for (int o = 0; o < 16; o++) {
        float s = sum[o], g = sq[o];
#pragma unroll
        for (int m = 1; m < 64; m <<= 1) { s += __shfl_xor(s, m); g += __shfl_xor(g, m); }
        if (lane == 0) { red[wv][o] = s; red[wv][16 + o] = g; }
    }
    __syncthreads();
    if (threadIdx.x < 32)
        p1[blockIdx.x * 32 + threadIdx.x] =
            red[0][threadIdx.x] + red[1][threadIdx.x] + red[2][threadIdx.x] + red[3][threadIdx.x];
}

// ---------------- kr1: reduce p1 -> scaled W1 + c1 ----------------
__global__ __launch_bounds__(256) void kr1(const float* __restrict__ p1,
                                           const float* __restrict__ W1,
                                           const float* __restrict__ g1,
                                           const float* __restrict__ b1,
                                           float* __restrict__ w1s,
                                           float* __restrict__ c1s) {
    __shared__ double acc[8][32];
    __shared__ float a1f[16];
    const int t = threadIdx.x;
    const int slot = t & 31, grp = t >> 5;
    double a = 0.0;
    for (int i = grp; i < 1024; i += 8) a += (double)p1[i * 32 + slot];
    acc[grp][slot] = a;
    __syncthreads();
    if (t < 16) {
        double s = 0, q = 0;
#pragma unroll
        for (int g = 0; g < 8; g++) { s += acc[g][t]; q += acc[g][16 + t]; }
        const double m = s * (1.0 / NPTS);
        const double v = q * (1.0 / NPTS) - m * m;
        const float inv = rsqrtf((float)v + 1e-3f);
        const float aa = g1[t] * inv;
        a1f[t] = aa;
        c1s[t] = b1[t] - (float)m * aa;
    }
    __syncthreads();
    if (t < 128) w1s[t] = a1f[t >> 3] * W1[t];
}

// ---------------- k2: split-bf16 MFMA layer-2, partial stats of h2pre ----------------
__global__ __launch_bounds__(256, 4) void k2(const float* __restrict__ vox,
                                             const int* __restrict__ coords,
                                             const int* __restrict__ nump,
                                             const float* __restrict__ w1s,
                                             const float* __restrict__ c1s,
                                             const float* __restrict__ W2,
                                             float* __restrict__ p2) {
    const int l = threadIdx.x & 63, wv = threadIdx.x >> 6;
    const int p = l & 31, hf = l >> 5;

    bf8v b1h, b1l, b2h, b2l;
#pragma unroll
    for (int i = 0; i < 8; i++) {
        short h_, l_;
        split2(W2[p * 32 + 8 * hf + i], &h_, &l_);       b1h[i] = h_; b1l[i] = l_;
        split2(W2[p * 32 + 16 + 8 * hf + i], &h_, &l_);  b2h[i] = h_; b2l[i] = l_;
    }

    float tsum = 0.f, tsq = 0.f;
    const int gw = blockIdx.x * 4 + wv;
#pragma unroll 1
    for (int v = 0; v < VPW; ++v) {
        const int vx = gw + v * NWAV;
        const int4 c4 = reinterpret_cast<const int4*>(coords)[vx];
        const int np = nump[vx];
        const float4 q = reinterpret_cast<const float4*>(vox)[(vx << 5) + p];
        const float cx = ((float)c4.w + 0.5f) * 0.16f;
        const float cy = ((float)c4.z + 0.5f) * 0.16f - 39.68f;
        const float cz = ((float)c4.y + 0.5f) * 4.0f  - 3.0f;
        const float f[8] = {q.x, q.y, q.z, q.x - cx, q.y - cy, q.z - cz, q.w, q.z};
        float mine[8], mx[8];
#pragma unroll
        for (int i = 0; i < 8; i++) {
            float s0 = c1s[i], s1 = c1s[8 + i];
#pragma unroll
            for (int c = 0; c < 8; c++) {
                s0 = fmaf(f[c], w1s[i * 8 + c], s0);
                s1 = fmaf(f[c], w1s[(8 + i) * 8 + c], s1);
            }
            mine[i] = fmaxf(hf ? s1 : s0, 0.f);
        }
#pragma unroll
        for (int i = 0; i < 8; i++) {
            float m = mine[i];
            m = fmaxf(m, __shfl_xor(m, 1));
            m = fmaxf(m, __shfl_xor(m, 2));
            m = fmaxf(m, __shfl_xor(m, 4));
            m = fmaxf(m, __shfl_xor(m, 8));
            m = fmaxf(m, __shfl_xor(m, 16));
            mx[i] = m;
        }
        const float mk = (p < np) ? 1.f : 0.f;
        bf8v a1h, a1l, a2h, a2l;
#pragma unroll
        for (int i = 0; i < 8; i++) {
            short h_, l_;
            split2(mk * mine[i], &h_, &l_);  a1h[i] = h_; a1l[i] = l_;
            split2(mk * mx[i], &h_, &l_);    a2h[i] = h_; a2l[i] = l_;
        }
        f16x d;
#pragma unroll
        for (int r = 0; r < 16; r++) d[r] = 0.f;
        d = __builtin_amdgcn_mfma_f32_32x32x16_bf16(a1h, b1h, d, 0, 0, 0);
        d = __builtin_amdgcn_mfma_f32_32x32x16_bf16(a1l, b1h, d, 0, 0, 0);
        d = __builtin_amdgcn_mfma_f32_32x32x16_bf16(a1h, b1l, d, 0, 0, 0);
        d = __builtin_amdgcn_mfma_f32_32x32x16_bf16(a2h, b2h, d, 0, 0, 0);
        d = __builtin_amdgcn_mfma_f32_32x32x16_bf16(a2l, b2h, d, 0, 0, 0);
        d = __builtin_amdgcn_mfma_f32_32x32x16_bf16(a2h, b2l, d, 0, 0, 0);
#pragma unroll
        for (int r = 0; r < 16; r++) { tsum += d[r]; tsq = fmaf(d[r], d[r], tsq); }
    }

    tsum += __shfl_xor(tsum, 32);
    tsq  += __shfl_xor(tsq, 32);
    __shared__ float red[4][64];
    if (l < 32) { red[wv][l] = tsum; red[wv][32 + l] = tsq; }
    __syncthreads();
    if (threadIdx.x < 64)
        p2[blockIdx.x * 64 + threadIdx.x] =
            red[0][threadIdx.x] + red[1][threadIdx.x] + red[2][threadIdx.x] + red[3][threadIdx.x];
}

// ---------------- kr2: reduce p2 -> a2/c2 ----------------
__global__ __launch_bounds__(256) void kr2(const float* __restrict__ p2,
                                           const float* __restrict__ g2,
                                           const float* __restrict__ b2,
                                           float* __restrict__ a2c2) {
    __shared__ double acc[4][64];
    const int t = threadIdx.x;
    const int slot = t & 63, grp = t >> 6;
    double a = 0.0;
    for (int i = grp; i < NBLK; i += 4) a += (double)p2[i * 64 + slot];
    acc[grp][slot] = a;
    __syncthreads();
    if (t < 32) {
        double s = 0, q = 0;
#pragma unroll
        for (int g = 0; g < 4; g++) { s += acc[g][t]; q += acc[g][32 + t]; }
        const double m = s * (1.0 / NPTS);
        const double v = q * (1.0 / NPTS) - m * m;
        const float inv = rsqrtf((float)v + 1e-3f);
        const float aa = g2[t] * inv;
        a2c2[t] = aa;
        a2c2[32 + t] = b2[t] - (float)m * aa;
    }
}

// ---------------- k3: split-bf16 MFMA layer-2, voxel features, fp32 final matmul ----------------
__global__ __launch_bounds__(256, 3) void k3(const float* __restrict__ vox,
                                             const int* __restrict__ coords,
                                             const int* __restrict__ nump,
                                             const float* __restrict__ w1s,
                                             const float* __restrict__ c1s,
                                             const float* __restrict__ W2,
                                             const float* __restrict__ a2c2,
                                             const float* __restrict__ Wf,
                                             float* __restrict__ p3,
                                             float* __restrict__ outp) {
    const int l = threadIdx.x & 63, wv = threadIdx.x >> 6;
    const int p = l & 31, hf = l >> 5;

    bf8v b1h, b1l, b2h, b2l;
#pragma unroll
    for (int i = 0; i < 8; i++) {
        short h_, l_;
        split2(W2[p * 32 + 8 * hf + i], &h_, &l_);       b1h[i] = h_; b1l[i] = l_;
        split2(W2[p * 32 + 16 + 8 * hf + i], &h_, &l_);  b2h[i] = h_; b2l[i] = l_;
    }
    const float a2v = a2c2[p];
    const float c2v = a2c2[32 + p];

    // Wf row l in fp32: 64 VGPRs
    float wfr[64];
#pragma unroll
    for (int j = 0; j < 16; j++) {
        const float4 w4 = reinterpret_cast<const float4*>(Wf)[l * 16 + j];
        wfr[4 * j] = w4.x; wfr[4 * j + 1] = w4.y; wfr[4 * j + 2] = w4.z; wfr[4 * j + 3] = w4.w;
    }

    __shared__ float red[4][128];

    float ts = 0.f, tq = 0.f;
    const int gw = blockIdx.x * 4 + wv;
#pragma unroll 1
    for (int v = 0; v < VPW; ++v) {
        const int vx = gw + v * NWAV;
        const int4 c4 = reinterpret_cast<const int4*>(coords)[vx];
        const int np = nump[vx];
        const float4 q = reinterpret_cast<const float4*>(vox)[(vx << 5) + p];
        const float cx = ((float)c4.w + 0.5f) * 0.16f;
        const float cy = ((float)c4.z + 0.5f) * 0.16f - 39.68f;
        const float cz = ((float)c4.y + 0.5f) * 4.0f  - 3.0f;
        const float f[8] = {q.x, q.y, q.z, q.x - cx, q.y - cy, q.z - cz, q.w, q.z};
        float mine[8], mx[8];
#pragma unroll
        for (int i = 0; i < 8; i++) {
            float s0 = c1s[i], s1 = c1s[8 + i];
#pragma unroll
            for (int c = 0; c < 8; c++) {
                s0 = fmaf(f[c], w1s[i * 8 + c], s0);
                s1 = fmaf(f[c], w1s[(8 + i) * 8 + c], s1);
            }
            mine[i] = fmaxf(hf ? s1 : s0, 0.f);
        }
#pragma unroll
        for (int i = 0; i < 8; i++) {
            float m = mine[i];
            m = fmaxf(m, __shfl_xor(m, 1));
            m = fmaxf(m, __shfl_xor(m, 2));
            m = fmaxf(m, __shfl_xor(m, 4));
            m = fmaxf(m, __shfl_xor(m, 8));
            m = fmaxf(m, __shfl_xor(m, 16));
            mx[i] = m;
        }
        const float mk = (p < np) ? 1.f : 0.f;
        bf8v a1h, a1l, a2h, a2l;
#pragma unroll
        for (int i = 0; i < 8; i++) {
            short h_, l_;
            split2(mk * mine[i], &h_, &l_);  a1h[i] = h_; a1l[i] = l_;
            split2(mk * mx[i], &h_, &l_);    a2h[i] = h_; a2l[i] = l_;
        }
        f16x d;
#pragma unroll
        for (int r = 0; r < 16; r++) d[r] = 0.f;
        d = __builtin_amdgcn_mfma_f32_32x32x16_bf16(a1h, b1h, d, 0, 0, 0);
        d = __builtin_amdgcn_mfma_f32_32x32x16_bf16(a1l, b1h, d, 0, 0, 0);
        d = __builtin_amdgcn_mfma_f32_32x32x16_bf16(a1h, b1l, d, 0, 0, 0);
        d = __builtin_amdgcn_mfma_f32_32x32x16_bf16(a2h, b2h, d, 0, 0, 0);
        d = __builtin_amdgcn_mfma_f32_32x32x16_bf16(a2l, b2h, d, 0, 0, 0);
        d = __builtin_amdgcn_mfma_f32_32x32x16_bf16(a2h, b2l, d, 0, 0, 0);

        // D: lane holds channel p, rows (r&3)+8*(r>>2)+4*hf
        float vfm = 0.f, vfa = 0.f;
#pragma unroll
        for (int r = 0; r < 16; r++) {
            const int row = (r & 3) + 8 * (r >> 2) + 4 * hf;
            const float h2 = fmaxf(fmaf(a2v, d[r], c2v), 0.f);
            vfa = fmaxf(vfa, h2);
            vfm = fmaxf(vfm, (row < np) ? h2 : 0.f);
        }
        vfm = fmaxf(vfm, __shfl_xor(vfm, 32));
        vfa = fmaxf(vfa, __shfl_xor(vfa, 32));
        // lane l holds vf[l]: channels 0..31 = masked max, 32..63 = gated unmasked max
        const float bc = hf ? ((np > 0) ? vfa : 0.f) : vfm;

        float o0 = 0.f, o1 = 0.f, o2 = 0.f, o3 = 0.f;
#pragma unroll
        for (int c = 0; c < 64; c += 4) {
            o0 = fmaf(rdlane(bc, c),     wfr[c],     o0);
            o1 = fmaf(rdlane(bc, c + 1), wfr[c + 1], o1);
            o2 = fmaf(rdlane(bc, c + 2), wfr[c + 2], o2);
            o3 = fmaf(rdlane(bc, c + 3), wfr[c + 3], o3);
        }
        const float out = (o0 + o1) + (o2 + o3);
        outp[vx * 64 + l] = out;
        ts += out;
        tq = fmaf(out, out, tq);
    }

    red[wv][l] = ts;
    red[wv][64 + l] = tq;
    __syncthreads();
    if (threadIdx.x < 128)
        p3[blockIdx.x * 128 + threadIdx.x] =
            red[0][threadIdx.x] + red[1][threadIdx.x] + red[2][threadIdx.x] + red[3][threadIdx.x];
}

// ---------------- kr3: reduce p3 -> af/cf ----------------
__global__ __launch_bounds__(256) void kr3(const float* __restrict__ p3,
                                           const float* __restrict__ gf,
                                           const float* __restrict__ bfv,
                                           float* __restrict__ afcf) {
    __shared__ double acc[2][128];
    const int t = threadIdx.x;
    const int slot = t & 127, grp = t >> 7;
    double a = 0.0;
    for (int i = grp; i < NBLK; i += 2) a += (double)p3[i * 128 + slot];
    acc[grp][slot] = a;
    __syncthreads();
    if (t < 64) {
        const double s = acc[0][t] + acc[1][t];
        const double q = acc[0][64 + t] + acc[1][64 + t];
        const double m = s * (1.0 / NVOX);
        const double v = q * (1.0 / NVOX) - m * m;
        const float inv = rsqrtf((float)v + 1e-5f);
        const float aa = gf[t] * inv;
        afcf[t] = aa;
        afcf[64 + t] = bfv[t] - (float)m * aa;
    }
}

// ---------------- k4: final BN, in-place, one float4 per thread ----------------
__global__ __launch_bounds__(256) void k4(float* __restrict__ outp,
                                          const float* __restrict__ afcf) {
    const int tid = blockIdx.x * blockDim.x + threadIdx.x;   // 512000 threads
    const int o = (tid * 4) & 63;
    float4 v = reinterpret_cast<float4*>(outp)[tid];
    v.x = fmaf(afcf[o],     v.x, afcf[64 + o]);
    v.y = fmaf(afcf[o + 1], v.y, afcf[65 + o]);
    v.z = fmaf(afcf[o + 2], v.z, afcf[66 + o]);
    v.w = fmaf(afcf[o + 3], v.w, afcf[67 + o]);
    reinterpret_cast<float4*>(outp)[tid] = v;
}

extern "C" void kernel_launch(void* const* d_in, const int* in_sizes, int n_in,
                              void* d_out, int out_size, void* d_ws, size_t ws_size,
                              hipStream_t stream) {
    const float* vox    = (const float*)d_in[0];
    const int*   coords = (const int*)d_in[1];
    const int*   nump   = (const int*)d_in[2];
    const float* W1     = (const float*)d_in[3];
    const float* g1     = (const float*)d_in[4];
    const float* b1     = (const float*)d_in[5];
    const float* W2     = (const float*)d_in[6];
    const float* g2     = (const float*)d_in[7];
    const float* b2     = (const float*)d_in[8];
    const float* Wf     = (const float*)d_in[9];
    const float* gf     = (const float*)d_in[10];
    const float* bfv    = (const float*)d_in[11];
    float* out = (float*)d_out;
    float* ws  = (float*)d_ws;

    float* W1S  = ws + O_W1S;
    float* C1S  = ws + O_C1S;
    float* A2C2 = ws + O_A2C2;
    float* AFCF = ws + O_AFCF;
    float* P1   = ws + O_P1;
    float* P2   = ws + O_P2;
    float* P3   = ws + O_P3;

    k1<<<1024, 256, 0, stream>>>(vox, coords, W1, P1);
    kr1<<<1, 256, 0, stream>>>(P1, W1, g1, b1, W1S, C1S);
    k2<<<NBLK, 256, 0, stream>>>(vox, coords, nump, W1S, C1S, W2, P2);
    kr2<<<1, 256, 0, stream>>>(P2, g2, b2, A2C2);
    k3<<<NBLK, 256, 0, stream>>>(vox, coords, nump, W1S, C1S, W2, A2C2, Wf, P3, out);
    kr3<<<1, 256, 0, stream>>>(P3, gf, bfv, AFCF);
    k4<<<2000, 256, 0, stream>>>(out, AFCF);
}

// Round 5
// 262.172 us; speedup vs baseline: 1.7214x; 1.7214x over previous
//
#include <hip/hip_runtime.h>

#define NVOX 32000
#define NPTS 1024000
#define NBLK 1000      // k2/k3 blocks (4 waves each -> 4000 waves)
#define NWAV 4000
#define VPW  8         // voxels per wave: 4000*8 = 32000

typedef __attribute__((ext_vector_type(8)))  short bf8v;   // 8 bf16 (4 VGPRs)
typedef __attribute__((ext_vector_type(16))) float f16x;   // MFMA 32x32 accum

// split x = hi + lo (both trunc-bf16); residual error ~2^-16 relative
__device__ __forceinline__ void split2(float x, short* hi, short* lo) {
    const unsigned u = __float_as_uint(x);
    *hi = (short)(u >> 16);
    const float r = x - __uint_as_float(u & 0xFFFF0000u);   // exact
    *lo = (short)(__float_as_uint(r) >> 16);
}
__device__ __forceinline__ float rdlane(float v, int l) {
    return __int_as_float(__builtin_amdgcn_readlane(__float_as_int(v), l));
}

// ws layout: doubles first (atomic accumulators), then float params
// doubles: s1[32] | s2[64] | sf[128]  = 224 doubles
// floats (offset in floats from ws base, after 224 doubles = 448 floats):
#define OF_W1S  448          // 128
#define OF_C1S  (448+128)    // 16
#define OF_A2C2 (448+144)    // 64
#define OF_AFCF (448+208)    // 128

// ---------------- kz: zero the stats accumulators ----------------
__global__ void kz(double* __restrict__ s) {
    if (threadIdx.x < 224) s[threadIdx.x] = 0.0;
}

// ---------------- k1: stats of h1pre (16 ch) over all points ----------------
__global__ __launch_bounds__(256) void k1(const float* __restrict__ vox,
                                          const int* __restrict__ coords,
                                          const float* __restrict__ W1,
                                          double* __restrict__ s1) {
    float sum[16], sq[16];
#pragma unroll
    for (int o = 0; o < 16; o++) { sum[o] = 0.f; sq[o] = 0.f; }
    const int stride = gridDim.x * blockDim.x;
    for (int i = blockIdx.x * blockDim.x + threadIdx.x; i < NPTS; i += stride) {
        const int vx = i >> 5;
        const float4 q = reinterpret_cast<const float4*>(vox)[i];
        const int4 c4 = reinterpret_cast<const int4*>(coords)[vx];
        const float cx = ((float)c4.w + 0.5f) * 0.16f;
        const float cy = ((float)c4.z + 0.5f) * 0.16f - 39.68f;
        const float cz = ((float)c4.y + 0.5f) * 4.0f  - 3.0f;
        const float f[8] = {q.x, q.y, q.z, q.x - cx, q.y - cy, q.z - cz, q.w, q.z};
#pragma unroll
        for (int o = 0; o < 16; o++) {
            float h = 0.f;
#pragma unroll
            for (int c = 0; c < 8; c++) h = fmaf(f[c], W1[o * 8 + c], h);
            sum[o] += h;
            sq[o] = fmaf(h, h, sq[o]);
        }
    }
    __shared__ float red[4][32];
    const int lane = threadIdx.x & 63, wv = threadIdx.x >> 6;
#pragma unroll
    for (int o = 0; o < 16; o++) {
        float s = sum[o], g = sq[o];
#pragma unroll
        for (int m = 1; m < 64; m <<= 1) { s += __shfl_xor(s, m); g += __shfl_xor(g, m); }
        if (lane == 0) { red[wv][o] = s; red[wv][16 + o] = g; }
    }
    __syncthreads();
    if (threadIdx.x < 32) {
        const float t = red[0][threadIdx.x] + red[1][threadIdx.x] +
                        red[2][threadIdx.x] + red[3][threadIdx.x];
        atomicAdd(&s1[threadIdx.x], (double)t);
    }
}

// ---------------- kr1: s1 -> scaled W1 + c1 (tiny) ----------------
__global__ __launch_bounds__(128) void kr1(const double* __restrict__ s1,
                                           const float* __restrict__ W1,
                                           const float* __restrict__ g1,
                                           const float* __restrict__ b1,
                                           float* __restrict__ w1s,
                                           float* __restrict__ c1s) {
    __shared__ float a1f[16];
    const int t = threadIdx.x;
    if (t < 16) {
        const double m = s1[t] * (1.0 / NPTS);
        const double v = s1[16 + t] * (1.0 / NPTS) - m * m;
        const float inv = rsqrtf((float)v + 1e-3f);
        const float aa = g1[t] * inv;
        a1f[t] = aa;
        c1s[t] = b1[t] - (float)m * aa;
    }
    __syncthreads();
    w1s[t] = a1f[t >> 3] * W1[t];
}

// ---------------- k2: split-bf16 MFMA layer-2, stats of h2pre ----------------
__global__ __launch_bounds__(256, 4) void k2(const float* __restrict__ vox,
                                             const int* __restrict__ coords,
                                             const int* __restrict__ nump,
                                             const float* __restrict__ w1s,
                                             const float* __restrict__ c1s,
                                             const float* __restrict__ W2,
                                             double* __restrict__ s2) {
    const int l = threadIdx.x & 63, wv = threadIdx.x >> 6;
    const int p = l & 31, hf = l >> 5;

    bf8v b1h, b1l, b2h, b2l;
#pragma unroll
    for (int i = 0; i < 8; i++) {
        short h_, l_;
        split2(W2[p * 32 + 8 * hf + i], &h_, &l_);       b1h[i] = h_; b1l[i] = l_;
        split2(W2[p * 32 + 16 + 8 * hf + i], &h_, &l_);  b2h[i] = h_; b2l[i] = l_;
    }

    float tsum = 0.f, tsq = 0.f;
    const int gw = blockIdx.x * 4 + wv;
#pragma unroll 1
    for (int v = 0; v < VPW; ++v) {
        const int vx = gw + v * NWAV;
        const int4 c4 = reinterpret_cast<const int4*>(coords)[vx];
        const int np = nump[vx];
        const float4 q = reinterpret_cast<const float4*>(vox)[(vx << 5) + p];
        const float cx = ((float)c4.w + 0.5f) * 0.16f;
        const float cy = ((float)c4.z + 0.5f) * 0.16f - 39.68f;
        const float cz = ((float)c4.y + 0.5f) * 4.0f  - 3.0f;
        const float f[8] = {q.x, q.y, q.z, q.x - cx, q.y - cy, q.z - cz, q.w, q.z};
        float mine[8], mx[8];
#pragma unroll
        for (int i = 0; i < 8; i++) {
            float s0 = c1s[i], s1v = c1s[8 + i];
#pragma unroll
            for (int c = 0; c < 8; c++) {
                s0 = fmaf(f[c], w1s[i * 8 + c], s0);
                s1v = fmaf(f[c], w1s[(8 + i) * 8 + c], s1v);
            }
            mine[i] = fmaxf(hf ? s1v : s0, 0.f);
        }
#pragma unroll
        for (int i = 0; i < 8; i++) {
            float m = mine[i];
            m = fmaxf(m, __shfl_xor(m, 1));
            m = fmaxf(m, __shfl_xor(m, 2));
            m = fmaxf(m, __shfl_xor(m, 4));
            m = fmaxf(m, __shfl_xor(m, 8));
            m = fmaxf(m, __shfl_xor(m, 16));
            mx[i] = m;
        }
        const float mk = (p < np) ? 1.f : 0.f;
        bf8v a1h, a1l, a2h, a2l;
#pragma unroll
        for (int i = 0; i < 8; i++) {
            short h_, l_;
            split2(mk * mine[i], &h_, &l_);  a1h[i] = h_; a1l[i] = l_;
            split2(mk * mx[i], &h_, &l_);    a2h[i] = h_; a2l[i] = l_;
        }
        f16x d;
#pragma unroll
        for (int r = 0; r < 16; r++) d[r] = 0.f;
        d = __builtin_amdgcn_mfma_f32_32x32x16_bf16(a1h, b1h, d, 0, 0, 0);
        d = __builtin_amdgcn_mfma_f32_32x32x16_bf16(a1l, b1h, d, 0, 0, 0);
        d = __builtin_amdgcn_mfma_f32_32x32x16_bf16(a1h, b1l, d, 0, 0, 0);
        d = __builtin_amdgcn_mfma_f32_32x32x16_bf16(a2h, b2h, d, 0, 0, 0);
        d = __builtin_amdgcn_mfma_f32_32x32x16_bf16(a2l, b2h, d, 0, 0, 0);
        d = __builtin_amdgcn_mfma_f32_32x32x16_bf16(a2h, b2l, d, 0, 0, 0);
#pragma unroll
        for (int r = 0; r < 16; r++) { tsum += d[r]; tsq = fmaf(d[r], d[r], tsq); }
    }

    tsum += __shfl_xor(tsum, 32);
    tsq  += __shfl_xor(tsq, 32);
    __shared__ float red[4][64];
    if (l < 32) { red[wv][l] = tsum; red[wv][32 + l] = tsq; }
    __syncthreads();
    if (threadIdx.x < 64) {
        const float t = red[0][threadIdx.x] + red[1][threadIdx.x] +
                        red[2][threadIdx.x] + red[3][threadIdx.x];
        atomicAdd(&s2[threadIdx.x], (double)t);
    }
}

// ---------------- kr2: s2 -> a2/c2 (tiny) ----------------
__global__ __launch_bounds__(64) void kr2(const double* __restrict__ s2,
                                          const float* __restrict__ g2,
                                          const float* __restrict__ b2,
                                          float* __restrict__ a2c2) {
    const int t = threadIdx.x;
    if (t < 32) {
        const double m = s2[t] * (1.0 / NPTS);
        const double v = s2[32 + t] * (1.0 / NPTS) - m * m;
        const float inv = rsqrtf((float)v + 1e-3f);
        const float aa = g2[t] * inv;
        a2c2[t] = aa;
        a2c2[32 + t] = b2[t] - (float)m * aa;
    }
}

// ---------------- k3: split-bf16 MFMA layer-2, voxel features, fp32 final matmul ----------------
__global__ __launch_bounds__(256, 3) void k3(const float* __restrict__ vox,
                                             const int* __restrict__ coords,
                                             const int* __restrict__ nump,
                                             const float* __restrict__ w1s,
                                             const float* __restrict__ c1s,
                                             const float* __restrict__ W2,
                                             const float* __restrict__ a2c2,
                                             const float* __restrict__ Wf,
                                             double* __restrict__ sf,
                                             float* __restrict__ outp) {
    const int l = threadIdx.x & 63, wv = threadIdx.x >> 6;
    const int p = l & 31, hf = l >> 5;

    bf8v b1h, b1l, b2h, b2l;
#pragma unroll
    for (int i = 0; i < 8; i++) {
        short h_, l_;
        split2(W2[p * 32 + 8 * hf + i], &h_, &l_);       b1h[i] = h_; b1l[i] = l_;
        split2(W2[p * 32 + 16 + 8 * hf + i], &h_, &l_);  b2h[i] = h_; b2l[i] = l_;
    }
    const float a2v = a2c2[p];
    const float c2v = a2c2[32 + p];

    // Wf row l in fp32: 64 VGPRs
    float wfr[64];
#pragma unroll
    for (int j = 0; j < 16; j++) {
        const float4 w4 = reinterpret_cast<const float4*>(Wf)[l * 16 + j];
        wfr[4 * j] = w4.x; wfr[4 * j + 1] = w4.y; wfr[4 * j + 2] = w4.z; wfr[4 * j + 3] = w4.w;
    }

    __shared__ float red[4][128];

    float ts = 0.f, tq = 0.f;
    const int gw = blockIdx.x * 4 + wv;
#pragma unroll 1
    for (int v = 0; v < VPW; ++v) {
        const int vx = gw + v * NWAV;
        const int4 c4 = reinterpret_cast<const int4*>(coords)[vx];
        const int np = nump[vx];
        const float4 q = reinterpret_cast<const float4*>(vox)[(vx << 5) + p];
        const float cx = ((float)c4.w + 0.5f) * 0.16f;
        const float cy = ((float)c4.z + 0.5f) * 0.16f - 39.68f;
        const float cz = ((float)c4.y + 0.5f) * 4.0f  - 3.0f;
        const float f[8] = {q.x, q.y, q.z, q.x - cx, q.y - cy, q.z - cz, q.w, q.z};
        float mine[8], mx[8];
#pragma unroll
        for (int i = 0; i < 8; i++) {
            float s0 = c1s[i], s1v = c1s[8 + i];
#pragma unroll
            for (int c = 0; c < 8; c++) {
                s0 = fmaf(f[c], w1s[i * 8 + c], s0);
                s1v = fmaf(f[c], w1s[(8 + i) * 8 + c], s1v);
            }
            mine[i] = fmaxf(hf ? s1v : s0, 0.f);
        }
#pragma unroll
        for (int i = 0; i < 8; i++) {
            float m = mine[i];
            m = fmaxf(m, __shfl_xor(m, 1));
            m = fmaxf(m, __shfl_xor(m, 2));
            m = fmaxf(m, __shfl_xor(m, 4));
            m = fmaxf(m, __shfl_xor(m, 8));
            m = fmaxf(m, __shfl_xor(m, 16));
            mx[i] = m;
        }
        const float mk = (p < np) ? 1.f : 0.f;
        bf8v a1h, a1l, a2h, a2l;
#pragma unroll
        for (int i = 0; i < 8; i++) {
            short h_, l_;
            split2(mk * mine[i], &h_, &l_);  a1h[i] = h_; a1l[i] = l_;
            split2(mk * mx[i], &h_, &l_);    a2h[i] = h_; a2l[i] = l_;
        }
        f16x d;
#pragma unroll
        for (int r = 0; r < 16; r++) d[r] = 0.f;
        d = __builtin_amdgcn_mfma_f32_32x32x16_bf16(a1h, b1h, d, 0, 0, 0);
        d = __builtin_amdgcn_mfma_f32_32x32x16_bf16(a1l, b1h, d, 0, 0, 0);
        d = __builtin_amdgcn_mfma_f32_32x32x16_bf16(a1h, b1l, d, 0, 0, 0);
        d = __builtin_amdgcn_mfma_f32_32x32x16_bf16(a2h, b2h, d, 0, 0, 0);
        d = __builtin_amdgcn_mfma_f32_32x32x16_bf16(a2l, b2h, d, 0, 0, 0);
        d = __builtin_amdgcn_mfma_f32_32x32x16_bf16(a2h, b2l, d, 0, 0, 0);

        // D: lane holds channel p, rows (r&3)+8*(r>>2)+4*hf
        float vfm = 0.f, vfa = 0.f;
#pragma unroll
        for (int r = 0; r < 16; r++) {
            const int row = (r & 3) + 8 * (r >> 2) + 4 * hf;
            const float h2 = fmaxf(fmaf(a2v, d[r], c2v), 0.f);
            vfa = fmaxf(vfa, h2);
            vfm = fmaxf(vfm, (row < np) ? h2 : 0.f);
        }
        vfm = fmaxf(vfm, __shfl_xor(vfm, 32));
        vfa = fmaxf(vfa, __shfl_xor(vfa, 32));
        // lane l holds vf[l]: channels 0..31 = masked max, 32..63 = gated unmasked max
        const float bc = hf ? ((np > 0) ? vfa : 0.f) : vfm;

        float o0 = 0.f, o1 = 0.f, o2 = 0.f, o3 = 0.f;
#pragma unroll
        for (int c = 0; c < 64; c += 4) {
            o0 = fmaf(rdlane(bc, c),     wfr[c],     o0);
            o1 = fmaf(rdlane(bc, c + 1), wfr[c + 1], o1);
            o2 = fmaf(rdlane(bc, c + 2), wfr[c + 2], o2);
            o3 = fmaf(rdlane(bc, c + 3), wfr[c + 3], o3);
        }
        const float out = (o0 + o1) + (o2 + o3);
        outp[vx * 64 + l] = out;
        ts += out;
        tq = fmaf(out, out, tq);
    }

    red[wv][l] = ts;
    red[wv][64 + l] = tq;
    __syncthreads();
    if (threadIdx.x < 128) {
        const float t = red[0][threadIdx.x] + red[1][threadIdx.x] +
                        red[2][threadIdx.x] + red[3][threadIdx.x];
        atomicAdd(&sf[threadIdx.x], (double)t);
    }
}

// ---------------- kr3: sf -> af/cf (tiny) ----------------
__global__ __launch_bounds__(64) void kr3(const double* __restrict__ sf,
                                          const float* __restrict__ gf,
                                          const float* __restrict__ bfv,
                                          float* __restrict__ afcf) {
    const int t = threadIdx.x;
    const double m = sf[t] * (1.0 / NVOX);
    const double v = sf[64 + t] * (1.0 / NVOX) - m * m;
    const float inv = rsqrtf((float)v + 1e-5f);
    const float aa = gf[t] * inv;
    afcf[t] = aa;
    afcf[64 + t] = bfv[t] - (float)m * aa;
}

// ---------------- k4: final BN, in-place, one float4 per thread ----------------
__global__ __launch_bounds__(256) void k4(float* __restrict__ outp,
                                          const float* __restrict__ afcf) {
    const int tid = blockIdx.x * blockDim.x + threadIdx.x;   // 512000 threads
    const int o = (tid * 4) & 63;
    float4 v = reinterpret_cast<float4*>(outp)[tid];
    v.x = fmaf(afcf[o],     v.x, afcf[64 + o]);
    v.y = fmaf(afcf[o + 1], v.y, afcf[65 + o]);
    v.z = fmaf(afcf[o + 2], v.z, afcf[66 + o]);
    v.w = fmaf(afcf[o + 3], v.w, afcf[67 + o]);
    reinterpret_cast<float4*>(outp)[tid] = v;
}

extern "C" void kernel_launch(void* const* d_in, const int* in_sizes, int n_in,
                              void* d_out, int out_size, void* d_ws, size_t ws_size,
                              hipStream_t stream) {
    const float* vox    = (const float*)d_in[0];
    const int*   coords = (const int*)d_in[1];
    const int*   nump   = (const int*)d_in[2];
    const float* W1     = (const float*)d_in[3];
    const float* g1     = (const float*)d_in[4];
    const float* b1     = (const float*)d_in[5];
    const float* W2     = (const float*)d_in[6];
    const float* g2     = (const float*)d_in[7];
    const float* b2     = (const float*)d_in[8];
    const float* Wf     = (const float*)d_in[9];
    const float* gf     = (const float*)d_in[10];
    const float* bfv    = (const float*)d_in[11];
    float* out = (float*)d_out;

    double* s1 = (double*)d_ws;          // 32
    double* s2 = s1 + 32;                // 64
    double* sf = s1 + 96;                // 128
    float*  wsf  = (float*)d_ws;
    float*  W1S  = wsf + OF_W1S;
    float*  C1S  = wsf + OF_C1S;
    float*  A2C2 = wsf + OF_A2C2;
    float*  AFCF = wsf + OF_AFCF;

    kz<<<1, 256, 0, stream>>>(s1);
    k1<<<1024, 256, 0, stream>>>(vox, coords, W1, s1);
    kr1<<<1, 128, 0, stream>>>(s1, W1, g1, b1, W1S, C1S);
    k2<<<NBLK, 256, 0, stream>>>(vox, coords, nump, W1S, C1S, W2, s2);
    kr2<<<1, 64, 0, stream>>>(s2, g2, b2, A2C2);
    k3<<<NBLK, 256, 0, stream>>>(vox, coords, nump, W1S, C1S, W2, A2C2, Wf, sf, out);
    kr3<<<1, 64, 0, stream>>>(sf, gf, bfv, AFCF);
    k4<<<2000, 256, 0, stream>>>(out, AFCF);
}

// Round 7
// 216.002 us; speedup vs baseline: 2.0893x; 1.2137x over previous
//
#include <hip/hip_runtime.h>

#define NVOX 32000
#define NPTS 1024000
#define NBLK 1000      // k2/k3 blocks (4 waves each -> 4000 waves)
#define NWAV 4000
#define VPW  8         // voxels per wave: 4000*8 = 32000
#define BIGF 1e30f

typedef __attribute__((ext_vector_type(8)))  short bf8v;   // 8 bf16 (4 VGPRs)
typedef __attribute__((ext_vector_type(16))) float f16x;   // MFMA 32x32 accum

// split x = hi + lo (both trunc-bf16); residual error ~2^-16 relative
__device__ __forceinline__ void split2(float x, short* hi, short* lo) {
    const unsigned u = __float_as_uint(x);
    *hi = (short)(u >> 16);
    const float r = x - __uint_as_float(u & 0xFFFF0000u);   // exact
    *lo = (short)(__float_as_uint(r) >> 16);
}
__device__ __forceinline__ float rdlane(float v, int l) {
    return __int_as_float(__builtin_amdgcn_readlane(__float_as_int(v), l));
}

// ws layout: doubles first (atomic accumulators), then float params
// doubles: sF[44] | s2[64] | sfin[128] = 236 doubles = 472 floats
#define OF_W1S  480          // 128
#define OF_C1S  (480+128)    // 16
#define OF_A2C2 (480+144)    // 64
#define OF_AFCF (480+208)    // 128

// ---------------- kz: zero the stats accumulators ----------------
__global__ void kz(double* __restrict__ s) {
    if (threadIdx.x < 236) s[threadIdx.x] = 0.0;
}

// ---------------- k1: moment accumulation (Sf[8], Sff upper[36]) ----------------
__global__ __launch_bounds__(256) void k1(const float* __restrict__ vox,
                                          const int* __restrict__ coords,
                                          double* __restrict__ sF) {
    float S[8], U[36];
#pragma unroll
    for (int a = 0; a < 8; a++) S[a] = 0.f;
#pragma unroll
    for (int a = 0; a < 36; a++) U[a] = 0.f;
    const int stride = gridDim.x * blockDim.x;
    for (int i = blockIdx.x * blockDim.x + threadIdx.x; i < NPTS; i += stride) {
        const int vx = i >> 5;
        const float4 q = reinterpret_cast<const float4*>(vox)[i];
        const int4 c4 = reinterpret_cast<const int4*>(coords)[vx];
        const float cx = ((float)c4.w + 0.5f) * 0.16f;
        const float cy = ((float)c4.z + 0.5f) * 0.16f - 39.68f;
        const float cz = ((float)c4.y + 0.5f) * 4.0f  - 3.0f;
        const float f[8] = {q.x, q.y, q.z, q.x - cx, q.y - cy, q.z - cz, q.w, q.z};
        int u = 0;
#pragma unroll
        for (int a = 0; a < 8; a++) {
            S[a] += f[a];
#pragma unroll
            for (int b = a; b < 8; b++) { U[u] = fmaf(f[a], f[b], U[u]); u++; }
        }
    }
    __shared__ float red[4][44];
    const int lane = threadIdx.x & 63, wv = threadIdx.x >> 6;
#pragma unroll
    for (int t = 0; t < 44; t++) {
        float s = (t < 8) ? S[t] : U[t - 8];
#pragma unroll
        for (int m = 1; m < 64; m <<= 1) s += __shfl_xor(s, m);
        if (lane == 0) red[wv][t] = s;
    }
    __syncthreads();
    if (threadIdx.x < 44) {
        const float t = red[0][threadIdx.x] + red[1][threadIdx.x] +
                        red[2][threadIdx.x] + red[3][threadIdx.x];
        atomicAdd(&sF[threadIdx.x], (double)t);
    }
}

// ---------------- kr1: moments -> h1 stats (quadratic form) -> scaled W1 + c1 ----------------
__global__ __launch_bounds__(128) void kr1(const double* __restrict__ sF,
                                           const float* __restrict__ W1,
                                           const float* __restrict__ g1,
                                           const float* __restrict__ b1,
                                           float* __restrict__ w1s,
                                           float* __restrict__ c1s) {
    __shared__ float a1f[16];
    const int t = threadIdx.x;
    if (t < 16) {
        double w[8];
#pragma unroll
        for (int c = 0; c < 8; c++) w[c] = (double)W1[t * 8 + c];
        double mu = 0.0;
#pragma unroll
        for (int c = 0; c < 8; c++) mu += w[c] * sF[c];
        double sq = 0.0;
        int u = 8;
        for (int a = 0; a < 8; a++)
            for (int b = a; b < 8; b++) {
                const double F = sF[u++];
                sq += (a == b ? 1.0 : 2.0) * w[a] * w[b] * F;
            }
        const double m = mu * (1.0 / NPTS);
        const double v = sq * (1.0 / NPTS) - m * m;
        const float inv = rsqrtf((float)v + 1e-3f);
        const float aa = g1[t] * inv;
        a1f[t] = aa;
        c1s[t] = b1[t] - (float)m * aa;
    }
    __syncthreads();
    w1s[t] = a1f[t >> 3] * W1[t];
}

// ---------------- k2: split-bf16 MFMA layer-2, stats of h2pre + fp32 extrema -> d_out ----------------
__global__ __launch_bounds__(256, 4) void k2(const float* __restrict__ vox,
                                             const int* __restrict__ coords,
                                             const int* __restrict__ nump,
                                             const float* __restrict__ w1s,
                                             const float* __restrict__ c1s,
                                             const float* __restrict__ W2,
                                             const float* __restrict__ g2,
                                             double* __restrict__ s2,
                                             float* __restrict__ outp) {
    const int l = threadIdx.x & 63, wv = threadIdx.x >> 6;
    const int p = l & 31, hf = l >> 5;

    bf8v b1h, b1l, b2h, b2l;
#pragma unroll
    for (int i = 0; i < 8; i++) {
        short h_, l_;
        split2(W2[p * 32 + 8 * hf + i], &h_, &l_);       b1h[i] = h_; b1l[i] = l_;
        split2(W2[p * 32 + 16 + 8 * hf + i], &h_, &l_);  b2h[i] = h_; b2l[i] = l_;
    }
    // sign(a2) == sign(g2) (inv-std > 0), so the relevant extremum (max if a2>=0,
    // min if a2<0) for channel p is known before the BN stats exist.
    const bool useMax = (g2[p] >= 0.f);

    float tsum = 0.f, tsq = 0.f;
    const int gw = blockIdx.x * 4 + wv;
#pragma unroll 1
    for (int v = 0; v < VPW; ++v) {
        const int vx = gw + v * NWAV;
        const int4 c4 = reinterpret_cast<const int4*>(coords)[vx];
        const int np = nump[vx];
        const float4 q = reinterpret_cast<const float4*>(vox)[(vx << 5) + p];
        const float cx = ((float)c4.w + 0.5f) * 0.16f;
        const float cy = ((float)c4.z + 0.5f) * 0.16f - 39.68f;
        const float cz = ((float)c4.y + 0.5f) * 4.0f  - 3.0f;
        const float f[8] = {q.x, q.y, q.z, q.x - cx, q.y - cy, q.z - cz, q.w, q.z};
        float mine[8], mx[8];
#pragma unroll
        for (int i = 0; i < 8; i++) {
            float s0 = c1s[i], s1v = c1s[8 + i];
#pragma unroll
            for (int c = 0; c < 8; c++) {
                s0 = fmaf(f[c], w1s[i * 8 + c], s0);
                s1v = fmaf(f[c], w1s[(8 + i) * 8 + c], s1v);
            }
            mine[i] = fmaxf(hf ? s1v : s0, 0.f);
        }
#pragma unroll
        for (int i = 0; i < 8; i++) {
            float m = mine[i];
            m = fmaxf(m, __shfl_xor(m, 1));
            m = fmaxf(m, __shfl_xor(m, 2));
            m = fmaxf(m, __shfl_xor(m, 4));
            m = fmaxf(m, __shfl_xor(m, 8));
            m = fmaxf(m, __shfl_xor(m, 16));
            mx[i] = m;
        }
        const float mk = (p < np) ? 1.f : 0.f;
        bf8v a1h, a1l, a2h, a2l;
#pragma unroll
        for (int i = 0; i < 8; i++) {
            short h_, l_;
            split2(mk * mine[i], &h_, &l_);  a1h[i] = h_; a1l[i] = l_;
            split2(mk * mx[i], &h_, &l_);    a2h[i] = h_; a2l[i] = l_;
        }
        f16x d;
#pragma unroll
        for (int r = 0; r < 16; r++) d[r] = 0.f;
        d = __builtin_amdgcn_mfma_f32_32x32x16_bf16(a1h, b1h, d, 0, 0, 0);
        d = __builtin_amdgcn_mfma_f32_32x32x16_bf16(a1l, b1h, d, 0, 0, 0);
        d = __builtin_amdgcn_mfma_f32_32x32x16_bf16(a1h, b1l, d, 0, 0, 0);
        d = __builtin_amdgcn_mfma_f32_32x32x16_bf16(a2h, b2h, d, 0, 0, 0);
        d = __builtin_amdgcn_mfma_f32_32x32x16_bf16(a2l, b2h, d, 0, 0, 0);
        d = __builtin_amdgcn_mfma_f32_32x32x16_bf16(a2h, b2l, d, 0, 0, 0);

        // stats + per-channel extrema (lane = channel p, rows (r&3)+8*(r>>2)+4*hf)
        float mmx = -BIGF, mmn = BIGF, fmx = -BIGF, fmn = BIGF;
#pragma unroll
        for (int r = 0; r < 16; r++) {
            const int row = (r & 3) + 8 * (r >> 2) + 4 * hf;
            const float x = d[r];
            tsum += x;
            tsq = fmaf(x, x, tsq);
            fmx = fmaxf(fmx, x);
            fmn = fminf(fmn, x);
            const bool in = row < np;
            mmx = fmaxf(mmx, in ? x : -BIGF);
            mmn = fminf(mmn, in ? x : BIGF);
        }
        mmx = fmaxf(mmx, __shfl_xor(mmx, 32));
        mmn = fminf(mmn, __shfl_xor(mmn, 32));
        fmx = fmaxf(fmx, __shfl_xor(fmx, 32));
        fmn = fminf(fmn, __shfl_xor(fmn, 32));
        // lane l<32: masked extremum of channel l; lane>=32: full extremum of channel l-32
        const float e = hf ? (useMax ? fmx : fmn) : (useMax ? mmx : mmn);
        outp[(vx << 6) + l] = e;
    }

    tsum += __shfl_xor(tsum, 32);
    tsq  += __shfl_xor(tsq, 32);
    __shared__ float red[4][64];
    if (l < 32) { red[wv][l] = tsum; red[wv][32 + l] = tsq; }
    __syncthreads();
    if (threadIdx.x < 64) {
        const float t = red[0][threadIdx.x] + red[1][threadIdx.x] +
                        red[2][threadIdx.x] + red[3][threadIdx.x];
        atomicAdd(&s2[threadIdx.x], (double)t);
    }
}

// ---------------- kr2: s2 -> a2/c2 (tiny) ----------------
__global__ __launch_bounds__(64) void kr2(const double* __restrict__ s2,
                                          const float* __restrict__ g2,
                                          const float* __restrict__ b2,
                                          float* __restrict__ a2c2) {
    const int t = threadIdx.x;
    if (t < 32) {
        const double m = s2[t] * (1.0 / NPTS);
        const double v = s2[32 + t] * (1.0 / NPTS) - m * m;
        const float inv = rsqrtf((float)v + 1e-3f);
        const float aa = g2[t] * inv;
        a2c2[t] = aa;
        a2c2[32 + t] = b2[t] - (float)m * aa;
    }
}

// ---------------- k3: extrema -> voxel features -> fp32 Wf dot, partial statsf ----------------
__global__ __launch_bounds__(256, 3) void k3(const int* __restrict__ nump,
                                             const float* __restrict__ a2c2,
                                             const float* __restrict__ Wf,
                                             double* __restrict__ sfin,
                                             float* __restrict__ outp) {
    const int l = threadIdx.x & 63, wv = threadIdx.x >> 6;
    const int p = l & 31;

    const float a2v = a2c2[p];
    const float c2v = a2c2[32 + p];

    // Wf row l in fp32: 64 VGPRs (body is small; these stay resident)
    float wfr[64];
#pragma unroll
    for (int j = 0; j < 16; j++) {
        const float4 w4 = reinterpret_cast<const float4*>(Wf)[l * 16 + j];
        wfr[4 * j] = w4.x; wfr[4 * j + 1] = w4.y; wfr[4 * j + 2] = w4.z; wfr[4 * j + 3] = w4.w;
    }

    __shared__ float red[4][128];

    float ts = 0.f, tq = 0.f;
    const int gw = blockIdx.x * 4 + wv;
#pragma unroll 1
    for (int v = 0; v < VPW; ++v) {
        const int vx = gw + v * NWAV;
        const int np = nump[vx];
        const float x = outp[(vx << 6) + l];        // relevant extremum, fp32
        const float h2 = fmaxf(fmaf(a2v, x, c2v), 0.f);
        const float bc = (np > 0) ? h2 : 0.f;       // lane l holds vf[l]

        float o0 = 0.f, o1 = 0.f, o2 = 0.f, o3 = 0.f;
#pragma unroll
        for (int c = 0; c < 64; c += 4) {
            o0 = fmaf(rdlane(bc, c),     wfr[c],     o0);
            o1 = fmaf(rdlane(bc, c + 1), wfr[c + 1], o1);
            o2 = fmaf(rdlane(bc, c + 2), wfr[c + 2], o2);
            o3 = fmaf(rdlane(bc, c + 3), wfr[c + 3], o3);
        }
        const float out = (o0 + o1) + (o2 + o3);
        outp[(vx << 6) + l] = out;
        ts += out;
        tq = fmaf(out, out, tq);
    }

    red[wv][l] = ts;
    red[wv][64 + l] = tq;
    __syncthreads();
    if (threadIdx.x < 128) {
        const float t = red[0][threadIdx.x] + red[1][threadIdx.x] +
                        red[2][threadIdx.x] + red[3][threadIdx.x];
        atomicAdd(&sfin[threadIdx.x], (double)t);
    }
}

// ---------------- kr3: sfin -> af/cf (tiny) ----------------
__global__ __launch_bounds__(64) void kr3(const double* __restrict__ sfin,
                                          const float* __restrict__ gf,
                                          const float* __restrict__ bfv,
                                          float* __restrict__ afcf) {
    const int t = threadIdx.x;
    const double m = sfin[t] * (1.0 / NVOX);
    const double v = sfin[64 + t] * (1.0 / NVOX) - m * m;
    const float inv = rsqrtf((float)v + 1e-5f);
    const float aa = gf[t] * inv;
    afcf[t] = aa;
    afcf[64 + t] = bfv[t] - (float)m * aa;
}

// ---------------- k4: final BN, in-place, one float4 per thread ----------------
__global__ __launch_bounds__(256) void k4(float* __restrict__ outp,
                                          const float* __restrict__ afcf) {
    const int tid = blockIdx.x * blockDim.x + threadIdx.x;   // 512000 threads
    const int o = (tid * 4) & 63;
    float4 v = reinterpret_cast<float4*>(outp)[tid];
    v.x = fmaf(afcf[o],     v.x, afcf[64 + o]);
    v.y = fmaf(afcf[o + 1], v.y, afcf[65 + o]);
    v.z = fmaf(afcf[o + 2], v.z, afcf[66 + o]);
    v.w = fmaf(afcf[o + 3], v.w, afcf[67 + o]);
    reinterpret_cast<float4*>(outp)[tid] = v;
}

extern "C" void kernel_launch(void* const* d_in, const int* in_sizes, int n_in,
                              void* d_out, int out_size, void* d_ws, size_t ws_size,
                              hipStream_t stream) {
    const float* vox    = (const float*)d_in[0];
    const int*   coords = (const int*)d_in[1];
    const int*   nump   = (const int*)d_in[2];
    const float* W1     = (const float*)d_in[3];
    const float* g1     = (const float*)d_in[4];
    const float* b1     = (const float*)d_in[5];
    const float* W2     = (const float*)d_in[6];
    const float* g2     = (const float*)d_in[7];
    const float* b2     = (const float*)d_in[8];
    const float* Wf     = (const float*)d_in[9];
    const float* gf     = (const float*)d_in[10];
    const float* bfv    = (const float*)d_in[11];
    float* out = (float*)d_out;

    double* sF   = (double*)d_ws;        // 44
    double* s2   = sF + 44;              // 64
    double* sfin = sF + 108;             // 128
    float*  wsf  = (float*)d_ws;
    float*  W1S  = wsf + OF_W1S;
    float*  C1S  = wsf + OF_C1S;
    float*  A2C2 = wsf + OF_A2C2;
    float*  AFCF = wsf + OF_AFCF;

    kz<<<1, 256, 0, stream>>>(sF);
    k1<<<1024, 256, 0, stream>>>(vox, coords, sF);
    kr1<<<1, 128, 0, stream>>>(sF, W1, g1, b1, W1S, C1S);
    k2<<<NBLK, 256, 0, stream>>>(vox, coords, nump, W1S, C1S, W2, g2, s2, out);
    kr2<<<1, 64, 0, stream>>>(s2, g2, b2, A2C2);
    k3<<<NBLK, 256, 0, stream>>>(nump, A2C2, Wf, sfin, out);
    kr3<<<1, 64, 0, stream>>>(sfin, gf, bfv, AFCF);
    k4<<<2000, 256, 0, stream>>>(out, AFCF);
}